// Round 9
// baseline (116.282 us; speedup 1.0000x reference)
//
#include <hip/hip_runtime.h>
#include <math.h>

#define SEQ   4096
#define NOBJ  32
#define IN_F  4
#define HID   64
#define IFEAT 8
#define NPAIR_HALF 496   // 32*31/2 unordered pairs; = 31 tiles * 16
#define NTILE 31

#define TWO_LOG2E 2.8853900817779268f   // 2*log2(e)
#define GP_CLAMP  10.0f                 // E=exp2(g') in [2^-10,2^10]: f16-safe

#if __has_builtin(__builtin_amdgcn_exp2f)
  #define EXP2F(x) __builtin_amdgcn_exp2f(x)
#else
  #define EXP2F(x) exp2f(x)
#endif

typedef _Float16 h2    __attribute__((ext_vector_type(2)));
typedef _Float16 f16x8 __attribute__((ext_vector_type(8)));
typedef short    s16x8 __attribute__((ext_vector_type(8)));
typedef float    f32x4 __attribute__((ext_vector_type(4)));

__device__ __forceinline__ h2 pack2(float a, float b) {
  return __builtin_bit_cast(h2, __builtin_amdgcn_cvt_pkrtz(a, b));
}
__device__ __forceinline__ unsigned pbits(h2 v) { return __builtin_bit_cast(unsigned, v); }

__device__ __forceinline__ f16x8 pack8(float4 a, float4 b) {
  int4 v;
  v.x = (int)pbits(pack2(a.x, a.y));
  v.y = (int)pbits(pack2(a.z, a.w));
  v.z = (int)pbits(pack2(b.x, b.y));
  v.w = (int)pbits(pack2(b.z, b.w));
  return __builtin_bit_cast(f16x8, v);
}

// Packed-f16 reciprocal: bit-trick guess + 2 Newton steps, all full-rate
// v_pk_* ops. Valid for x in [2^-9, 2^11] (su = Ei+Fj, E in [2^-10,2^10]).
__device__ __forceinline__ f16x8 rcp8nr(f16x8 x) {
  const s16x8 magic = (short)0x7799;
  f16x8 r = __builtin_bit_cast(f16x8, (s16x8)(magic - __builtin_bit_cast(s16x8, x)));
  const f16x8 two = (_Float16)2.0f;
  const f16x8 nx = -x;
#if __has_builtin(__builtin_elementwise_fma)
  r = r * __builtin_elementwise_fma(nx, r, two);
  r = r * __builtin_elementwise_fma(nx, r, two);
#else
  r = r * (nx * r + two);
  r = r * (nx * r + two);
#endif
  return r;
}

// f16 dot2 with f32 accumulate (v_dot2_f32_f16)
__device__ __forceinline__ float dot2h(h2 a, h2 b, float c) {
#if __has_builtin(__builtin_amdgcn_fdot2)
  return __builtin_amdgcn_fdot2(a, b, c, false);
#else
  float r = c;
  r = fmaf((float)a.x, (float)b.x, r);
  r = fmaf((float)a.y, (float)b.y, r);
  return r;
#endif
}

// lane^8 within each 16-lane row: DPP row_ror:8 (pure VALU, no LDS pipe)
__device__ __forceinline__ float xor8_f32(float v) {
#if __has_builtin(__builtin_amdgcn_mov_dpp)
  return __builtin_bit_cast(float,
      __builtin_amdgcn_mov_dpp(__builtin_bit_cast(int, v), 0x128, 0xF, 0xF, true));
#else
  return __shfl_xor(v, 8, 16);
#endif
}

// cumulative pair count before row i (i<j ordering): C(i) = i*(63-i)/2
__device__ __forceinline__ int pair_cum(int i) { return (i * (63 - i)) >> 1; }

__device__ __forceinline__ void pair_decode(int q, int& i, int& j) {
  int ii = (int)((63.0f - sqrtf(3969.0f - 8.0f * (float)q)) * 0.5f);
  if (ii > 0 && pair_cum(ii) > q) --ii;   // fp rounding fixups
  if (pair_cum(ii + 1) <= q)     ++ii;
  i = ii;
  j = ii + 1 + (q - pair_cum(ii));
}

// R21: R13 rerun WITHOUT the VGPR crush. 512 thr / 8 waves, one ss per wave
// (wq=wv&3, ssw=wv>>2); __launch_bounds__(512,4) -> empirical VGPR cap 64
// (R13's (512,8) capped at 32 -> remat; R16's (256,5) capped 48 -> spill).
// 4 blocks/CU x 8 waves = 32 waves/CU = 8 waves/SIMD (2x latency hiding;
// VALUBusy was 60% with 40% correlated-stall idle at 4 waves/SIMD).
// R14 tanh merge retained across r-pairs instead of ss (same trans count:
// lanes 8-15 take c[r+1] via DPP, write row r+1). 4b m-split 4-way
// (part[512] fills the wB alias exactly). Validity check: FETCH/WRITE must
// stay ~1.37/1.0 MB (no spill signature).
__global__ __launch_bounds__(512, 4) void magnet_fused(
    const float* __restrict__ x,      // [S,32,4]
    const float* __restrict__ L1W,    // [64,4]
    const float* __restrict__ L1b,    // [64]
    const float* __restrict__ L2W,    // [64,64]
    const float* __restrict__ L2b,    // [64]
    const float* __restrict__ I1W,    // [64,64]
    const float* __restrict__ I2W,    // [8,64]
    const float* __restrict__ I3,     // [992,2,4]
    const float* __restrict__ S1W,    // [4,4]
    const float* __restrict__ S1b,    // [4]
    const float* __restrict__ S2W,    // [32,2,2]
    const float* __restrict__ S2b,    // [32,2]
    float* __restrict__ out)          // [S,32,2]
{
  // LDS layout (float units), 8536 floats = 34144 B -> 4 blocks/CU:
  //   [0,1152)     sAtp s0 (ph1 write, ph2 read; never overwritten)
  //   [1152,2304)  sAtp s1
  //   [0,2480)     sv s0: f16[496][10] (4a write, 4b read; sAtp dead)
  //   [2480,3632)  sBtp s0 (ph2 write, ph3 read)
  //   [3632,4784)  sBtp s1
  //   [2480,4960)  sv s1 (4a write; sBtp dead, ph3-end barrier separates)
  //   [4960,6112)  sE s0: f16[32][72] (ph3 write, 4a read)
  //   [6112,7264)  sE s1
  //   [4960,5024)  swpart [64] (init write, combine read pre-ph2; sE later)
  //   [7264,7776)  wB [16][32] uint / part[512] (4b alias, exactly 512)
  //   [8032,8040)  sW [8]
  //   [8040,8536)  ptab32 [496] u32: (i*36)<<16 | (j*36)
  __shared__ __align__(16) float smem[8536];
  unsigned*       sEd0 = (unsigned*)(smem + 4960);  // dword view of f16 E
  unsigned*       wB   = (unsigned*)(smem + 7264);  // [16][32]
  float*          part = smem + 7264;               // [512] (aliases wB)
  float*          sW   = smem + 8032;               // [8]
  unsigned*       ptab32 = (unsigned*)(smem + 8040); // [496]
  float*          swpart = smem + 4960;             // [64] (aliases sE s0)

  const int t  = threadIdx.x;
  const int s0 = blockIdx.x * 2;

  // ---- init (no barrier after; consumers are beyond later barriers) ----
  if (t < 64) {                                // sW partials (distributed)
    const int f = t >> 3, seg = t & 7;
    const float4 a = *(const float4*)(I2W + f * HID + seg * 8);
    const float4 b = *(const float4*)(I2W + f * HID + seg * 8 + 4);
    swpart[t] = ((a.x + a.y) + (a.z + a.w)) + ((b.x + b.y) + (b.z + b.w));
  }
  {                                            // wB[n][k2]; rows 8-15 zero
    const int n = t >> 5, k2 = t & 31;
    wB[t] = (n < IFEAT)
      ? pbits(pack2(I2W[n * HID + 2 * k2], I2W[n * HID + 2 * k2 + 1])) : 0u;
  }
  if (t < NPAIR_HALF) {                        // 4a table: premult row offsets
    int i, j; pair_decode(t, i, j);
    ptab32[t] = ((unsigned)(i * 36) << 16) | (unsigned)(j * 36);
  }

  // ---- phase 1: h1 = relu(x @ L1W^T + L1b); x straight from global (L2).
  // 512 threads: one (ss, n, 8 k-rows) each. pack f16 -> sAtp(ss)[n][k2] ----
  {
    const int n = t & 31, gI = (t >> 5) & 7, ssp = t >> 8, kb = gI * 8;
    const float4 xv = *(const float4*)(x + s0 * 128 + ssp * 128 + n * 4);
    float a[8];
    #pragma unroll
    for (int r = 0; r < 8; ++r) {
      const int k = kb + r;
      const float4 w = *(const float4*)(L1W + k * 4);
      float v = L1b[k];
      v = fmaf(xv.x, w.x, v); v = fmaf(xv.y, w.y, v);
      v = fmaf(xv.z, w.z, v); v = fmaf(xv.w, w.w, v);
      a[r] = fmaxf(v, 0.0f);
    }
    unsigned* sAtp = (unsigned*)(smem + ssp * 1152);
    int4 pk;
    pk.x = (int)pbits(pack2(a[0], a[1]));
    pk.y = (int)pbits(pack2(a[2], a[3]));
    pk.z = (int)pbits(pack2(a[4], a[5]));
    pk.w = (int)pbits(pack2(a[6], a[7]));
    *(int4*)(sAtp + n * 36 + gI * 4) = pk;
  }
  __syncthreads();

  if (t < IFEAT) {                             // combine sW partials
    float a = 0.0f;
    #pragma unroll
    for (int c = 0; c < 8; ++c) a += swpart[t * 8 + c];
    sW[t] = a;                                 // read in 4a (barriers cover)
  }

  const int lane = t & 63;
  const int wv   = t >> 6;        // wave id 0..7
  const int wq   = wv & 3;        // wave-within-ss
  const int ssw  = wv >> 2;       // wave's sequence slot
  const int qd   = lane >> 4;     // quad 0..3
  const int ln   = lane & 15;

  // ---- phase 2: h2 = relu(h1 @ L2W^T + L2b) via MFMA; one ss per wave;
  // write sBtp directly (separate region -> no mid-barrier) ----
  {
    const int m = 16 * wq + ln;
    const float* wr = L2W + m * HID;
    const f16x8 A0 = pack8(*(const float4*)(wr + 8 * qd),
                           *(const float4*)(wr + 8 * qd + 4));
    const f16x8 A1 = pack8(*(const float4*)(wr + 32 + 8 * qd),
                           *(const float4*)(wr + 32 + 8 * qd + 4));
    const float4 bias = *(const float4*)(L2b + 16 * wq + 4 * qd);
    const unsigned* sAtp = (const unsigned*)(smem + ssw * 1152);
    unsigned* sBtp = (unsigned*)(smem + 2480 + ssw * 1152);
    #pragma unroll
    for (int nt = 0; nt < 2; ++nt) {
      const int n = nt * 16 + ln;
      const f16x8 B0 = __builtin_bit_cast(f16x8, *(const int4*)(sAtp + n * 36 + 4 * qd));
      const f16x8 B1 = __builtin_bit_cast(f16x8, *(const int4*)(sAtp + n * 36 + 16 + 4 * qd));
      f32x4 c; c[0] = bias.x; c[1] = bias.y; c[2] = bias.z; c[3] = bias.w;
      c = __builtin_amdgcn_mfma_f32_16x16x32_f16(A0, B0, c, 0, 0, 0);
      c = __builtin_amdgcn_mfma_f32_16x16x32_f16(A1, B1, c, 0, 0, 0);
      sBtp[n * 36 + 8 * wq + 2 * qd]     = pbits(pack2(fmaxf(c[0], 0.f), fmaxf(c[1], 0.f)));
      sBtp[n * 36 + 8 * wq + 2 * qd + 1] = pbits(pack2(fmaxf(c[2], 0.f), fmaxf(c[3], 0.f)));
    }
  }
  __syncthreads();

  // ---- phase 3: g' = h2 @ (I1W*2log2e)^T via MFMA; one ss per wave;
  // store E = exp2(g') as f16 pairs ----
  {
    const int m = 16 * wq + ln;
    const float* wr = I1W + m * HID;
    float4 w0 = *(const float4*)(wr + 8 * qd);
    float4 w1 = *(const float4*)(wr + 8 * qd + 4);
    float4 w2 = *(const float4*)(wr + 32 + 8 * qd);
    float4 w3 = *(const float4*)(wr + 32 + 8 * qd + 4);
    const float T = TWO_LOG2E;
    w0.x *= T; w0.y *= T; w0.z *= T; w0.w *= T;
    w1.x *= T; w1.y *= T; w1.z *= T; w1.w *= T;
    w2.x *= T; w2.y *= T; w2.z *= T; w2.w *= T;
    w3.x *= T; w3.y *= T; w3.z *= T; w3.w *= T;
    const f16x8 A0 = pack8(w0, w1);
    const f16x8 A1 = pack8(w2, w3);
    const unsigned* sBtp = (const unsigned*)(smem + 2480 + ssw * 1152);
    unsigned* sEd = sEd0 + ssw * 1152;
    #pragma unroll
    for (int nt = 0; nt < 2; ++nt) {
      const int n = nt * 16 + ln;
      const f16x8 B0 = __builtin_bit_cast(f16x8, *(const int4*)(sBtp + n * 36 + 4 * qd));
      const f16x8 B1 = __builtin_bit_cast(f16x8, *(const int4*)(sBtp + n * 36 + 16 + 4 * qd));
      f32x4 c; c[0] = 0.f; c[1] = 0.f; c[2] = 0.f; c[3] = 0.f;
      c = __builtin_amdgcn_mfma_f32_16x16x32_f16(A0, B0, c, 0, 0, 0);
      c = __builtin_amdgcn_mfma_f32_16x16x32_f16(A1, B1, c, 0, 0, 0);
      float e[4];
      #pragma unroll
      for (int r = 0; r < 4; ++r) {
        float gp = fminf(fmaxf(c[r], -GP_CLAMP), GP_CLAMP);   // c is g'
        e[r] = EXP2F(gp);
      }
      // mo = 16wq+4qd+r; f16 idx n*72+mo -> dword n*36 + 8wq + 2qd + {0,1}
      sEd[n * 36 + 8 * wq + 2 * qd]     = pbits(pack2(e[0], e[1]));
      sEd[n * 36 + 8 * wq + 2 * qd + 1] = pbits(pack2(e[2], e[3]));
    }
  }
  __syncthreads();   // sBtp reads done + sE settled before 4a overwrites sv

  // ---- phase 4a: pair dots via MFMA; one ss per wave, 4 waves per ss.
  // A = fj * rcp8nr(ei + fj). tanh merged across r-PAIRS via DPP:
  // lanes 8-15 (zero cols) take c[r+1] from lanes 0-7, write row r+1.
  // Same transcendental count per ss as the old ss-merge. ----
  {
    const f16x8 B0 = __builtin_bit_cast(f16x8, *(const int4*)(wB + ln * 32 + 4 * qd));
    const f16x8 B1 = __builtin_bit_cast(f16x8, *(const int4*)(wB + ln * 32 + 16 + 4 * qd));
    const float WfT = sW[ln & 7] * TWO_LOG2E;
    const float n2T = -2.0f * TWO_LOG2E;
    const bool lo = (ln < IFEAT);
    const unsigned* sEd = sEd0 + ssw * 1152;
    _Float16* svb = ssw ? (_Float16*)(smem + 2480) : (_Float16*)smem;
    const int col = ln & 7;
    const int rofs = lo ? 0 : 1;

    unsigned pijr[8];
    #pragma unroll
    for (int it = 0; it < 8; ++it) {
      const int tl = wq + it * 4;
      pijr[it] = ptab32[(tl < NTILE ? tl : 0) * 16 + ln];
    }

    #pragma unroll 2
    for (int it = 0; it < 8; ++it) {
      const int tile = wq + it * 4;
      if (tile < NTILE) {
        const unsigned pij = pijr[it];                 // (i*36)<<16 | (j*36)
        const int io = (int)(pij >> 16), jo = (int)(pij & 0xffffu);
        const f16x8 ei0 = __builtin_bit_cast(f16x8, *(const int4*)(sEd + io + 4 * qd));
        const f16x8 ei1 = __builtin_bit_cast(f16x8, *(const int4*)(sEd + io + 16 + 4 * qd));
        const f16x8 fj0 = __builtin_bit_cast(f16x8, *(const int4*)(sEd + jo + 4 * qd));
        const f16x8 fj1 = __builtin_bit_cast(f16x8, *(const int4*)(sEd + jo + 16 + 4 * qd));
        const f16x8 su0 = ei0 + fj0;               // v_pk_add_f16
        const f16x8 su1 = ei1 + fj1;
        const f16x8 A0 = fj0 * rcp8nr(su0);        // all full-rate pk ops
        const f16x8 A1 = fj1 * rcp8nr(su1);
        f32x4 c; c[0] = 0.f; c[1] = 0.f; c[2] = 0.f; c[3] = 0.f;
        c = __builtin_amdgcn_mfma_f32_16x16x32_f16(A0, B0, c, 0, 0, 0);
        c = __builtin_amdgcn_mfma_f32_16x16x32_f16(A1, B1, c, 0, 0, 0);
        #pragma unroll
        for (int rb = 0; rb < 4; rb += 2) {
          const float cns = xor8_f32(c[rb + 1]);  // c[rb+1] cols0-7 -> lanes 8-15
          const float m = lo ? c[rb] : cns;
          // tanh(Wf - 2c) = 1 - 2/(exp2((Wf-2c)*T)+1), T-scale pre-folded
          const float arg = fmaf(n2T, m, WfT);
          const float e = EXP2F(arg);
          const float rr = __builtin_amdgcn_rcpf(e + 1.0f);
          const float v = fmaf(-2.0f, rr, 1.0f);
          svb[(tile * 16 + 4 * qd + rb + rofs) * 10 + col] = (_Float16)v;
        }
      }
    }
  }
  __syncthreads();   // sv complete; wB dead -> part may overwrite

  // ---- phase 4b: thread = (ss, i, d, mq); INLINE index calc; 4-way m-split ----
  {
    const int ssp = t >> 8, i = (t >> 3) & 31, d = (t >> 2) & 1, mq = t & 3;
    const _Float16* sv = ssp ? (const _Float16*)(smem + 2480) : (const _Float16*)smem;
    const int msta = mq * 8;
    const int Ci = pair_cum(i);
    float sum = 0.0f;
    #pragma unroll
    for (int it = 0; it < 8; ++it) {
      const int m = msta + it;
      if (m < 31) {
        const bool up = (m >= i);                    // j = m+1 > i
        const int q = up ? (Ci + m - i) : (pair_cum(m) + i - m - 1);
        const h2* vp = (const h2*)(sv + q * 10 + d * 4);
        const h2 va = vp[0], vb = vp[1];
        const float4 cf = *(const float4*)(I3 + (i * 31 + m) * 8 + d * 4);
        const h2 ca = pack2(cf.x, cf.y);
        const h2 cb = pack2(cf.z, cf.w);
        float dot = dot2h(va, ca, 0.0f);
        dot = dot2h(vb, cb, dot);
        const float sgn = up ? 1.0f : -1.0f;
        sum = fmaf(sgn, dot, sum);
      }
    }
    part[t] = sum;
  }
  __syncthreads();

  // ---- final: combine partials + self term + store; x from global ----
  if (t < 128) {
    const int ssp = t >> 6, i = (t >> 1) & 31, d = t & 1;
    const int pbase = ssp * 256 + i * 8 + d * 4;
    float sum = (part[pbase] + part[pbase + 1]) + (part[pbase + 2] + part[pbase + 3]);

    float res = S2b[i * 2 + d] + sum;
    const float4 xv = *(const float4*)(x + (s0 + ssp) * 128 + i * 4);
    #pragma unroll
    for (int k = 0; k < 2; ++k) {
      const int f = d * 2 + k;
      float hs = S1b[f];
      hs = fmaf(xv.x, S1W[f * 4 + 0], hs);
      hs = fmaf(xv.y, S1W[f * 4 + 1], hs);
      hs = fmaf(xv.z, S1W[f * 4 + 2], hs);
      hs = fmaf(xv.w, S1W[f * 4 + 3], hs);
      hs = fmaxf(hs, 0.0f);
      res = fmaf(hs, S2W[i * 4 + d * 2 + k], res);
    }
    out[(s0 + ssp) * (NOBJ * 2) + i * 2 + d] = res;
  }
}

extern "C" void kernel_launch(void* const* d_in, const int* in_sizes, int n_in,
                              void* d_out, int out_size, void* d_ws, size_t ws_size,
                              hipStream_t stream) {
  const float* x   = (const float*)d_in[0];
  const float* L1W = (const float*)d_in[1];
  const float* L1b = (const float*)d_in[2];
  const float* L2W = (const float*)d_in[3];
  const float* L2b = (const float*)d_in[4];
  const float* I1W = (const float*)d_in[5];
  const float* I2W = (const float*)d_in[6];
  const float* I3  = (const float*)d_in[7];
  const float* S1W = (const float*)d_in[8];
  const float* S1b = (const float*)d_in[9];
  const float* S2W = (const float*)d_in[10];
  const float* S2b = (const float*)d_in[11];
  float* outp = (float*)d_out;

  magnet_fused<<<SEQ / 2, 512, 0, stream>>>(x, L1W, L1b, L2W, L2b, I1W, I2W, I3,
                                            S1W, S1b, S2W, S2b, outp);
}

// Round 10
// 109.602 us; speedup vs baseline: 1.0610x; 1.0610x over previous
//
#include <hip/hip_runtime.h>
#include <math.h>

#define SEQ   4096
#define NOBJ  32
#define IN_F  4
#define HID   64
#define IFEAT 8
#define NPAIR_HALF 496   // 32*31/2 unordered pairs; = 31 tiles * 16
#define NTILE 31

#define TWO_LOG2E 2.8853900817779268f   // 2*log2(e)
#define GP_CLAMP  10.0f                 // E=exp2(g') in [2^-10,2^10]: f16-safe

#if __has_builtin(__builtin_amdgcn_exp2f)
  #define EXP2F(x) __builtin_amdgcn_exp2f(x)
#else
  #define EXP2F(x) exp2f(x)
#endif

typedef _Float16 h2    __attribute__((ext_vector_type(2)));
typedef _Float16 f16x8 __attribute__((ext_vector_type(8)));
typedef short    s16x8 __attribute__((ext_vector_type(8)));
typedef float    f32x4 __attribute__((ext_vector_type(4)));

__device__ __forceinline__ h2 pack2(float a, float b) {
  return __builtin_bit_cast(h2, __builtin_amdgcn_cvt_pkrtz(a, b));
}
__device__ __forceinline__ unsigned pbits(h2 v) { return __builtin_bit_cast(unsigned, v); }

__device__ __forceinline__ f16x8 pack8(float4 a, float4 b) {
  int4 v;
  v.x = (int)pbits(pack2(a.x, a.y));
  v.y = (int)pbits(pack2(a.z, a.w));
  v.z = (int)pbits(pack2(b.x, b.y));
  v.w = (int)pbits(pack2(b.z, b.w));
  return __builtin_bit_cast(f16x8, v);
}

// Packed-f16 reciprocal: bit-trick guess + 2 Newton steps, all full-rate
// v_pk_* ops. Valid for x in [2^-9, 2^11] (su = Ei+Fj, E in [2^-10,2^10]).
__device__ __forceinline__ f16x8 rcp8nr(f16x8 x) {
  const s16x8 magic = (short)0x7799;
  f16x8 r = __builtin_bit_cast(f16x8, (s16x8)(magic - __builtin_bit_cast(s16x8, x)));
  const f16x8 two = (_Float16)2.0f;
  const f16x8 nx = -x;
#if __has_builtin(__builtin_elementwise_fma)
  r = r * __builtin_elementwise_fma(nx, r, two);
  r = r * __builtin_elementwise_fma(nx, r, two);
#else
  r = r * (nx * r + two);
  r = r * (nx * r + two);
#endif
  return r;
}

// f16 dot2 with f32 accumulate (v_dot2_f32_f16)
__device__ __forceinline__ float dot2h(h2 a, h2 b, float c) {
#if __has_builtin(__builtin_amdgcn_fdot2)
  return __builtin_amdgcn_fdot2(a, b, c, false);
#else
  float r = c;
  r = fmaf((float)a.x, (float)b.x, r);
  r = fmaf((float)a.y, (float)b.y, r);
  return r;
#endif
}

// lane^8 within each 16-lane row: DPP row_ror:8 (pure VALU, no LDS pipe)
__device__ __forceinline__ float xor8_f32(float v) {
#if __has_builtin(__builtin_amdgcn_mov_dpp)
  return __builtin_bit_cast(float,
      __builtin_amdgcn_mov_dpp(__builtin_bit_cast(int, v), 0x128, 0xF, 0xF, true));
#else
  return __shfl_xor(v, 8, 16);
#endif
}

// cumulative pair count before row i (i<j ordering): C(i) = i*(63-i)/2
__device__ __forceinline__ int pair_cum(int i) { return (i * (63 - i)) >> 1; }

__device__ __forceinline__ void pair_decode(int q, int& i, int& j) {
  int ii = (int)((63.0f - sqrtf(3969.0f - 8.0f * (float)q)) * 0.5f);
  if (ii > 0 && pair_cum(ii) > q) --ii;   // fp rounding fixups
  if (pair_cum(ii + 1) <= q)     ++ii;
  i = ii;
  j = ii + 1 + (q - pair_cum(ii));
}

// R22: traversal-amortization round. Model reconciling R13-R21 nulls: wall =
// (#blocks per CU) x (serial phase-chain latency per block); occupancy /
// conflicts / VALU count / barrier count all null because each attacks a
// slice of a chain traversed 8x per CU. This round: 4 seq per block ->
// 1024 blocks (4/CU, 2 resident), traversals 8 -> 4; weights/tables/chain
// fixed costs amortized over 4 ss. 4b fused with final (thread=(ss,i,d)
// does the full 31-m sum + self term; part[] + one barrier deleted).
// 256 thr / (256,4) kept — only config with proven-sane codegen (R13/R16/
// R21: any other launch_bounds crushes VGPR to 32-48 and remats/spills).
// LDS 62176 B -> 2 blocks/CU. Validity: FETCH/WRITE must stay ~1.37/1.0 MB.
__global__ __launch_bounds__(256, 4) void magnet_fused(
    const float* __restrict__ x,      // [S,32,4]
    const float* __restrict__ L1W,    // [64,4]
    const float* __restrict__ L1b,    // [64]
    const float* __restrict__ L2W,    // [64,64]
    const float* __restrict__ L2b,    // [64]
    const float* __restrict__ I1W,    // [64,64]
    const float* __restrict__ I2W,    // [8,64]
    const float* __restrict__ I3,     // [992,2,4]
    const float* __restrict__ S1W,    // [4,4]
    const float* __restrict__ S1b,    // [4]
    const float* __restrict__ S2W,    // [32,2,2]
    const float* __restrict__ S2b,    // [32,2]
    float* __restrict__ out)          // [S,32,2]
{
  // LDS layout (float units), 15544 floats = 62176 B -> 2 blocks/CU:
  //   [0,9920)      sv s0..s3: f16[496][10] each (2480 fl/ss; 4a wr, 4b rd)
  //   [0,4608)      sAtp s0..s3 (ph1 wr, ph2 rd; aliases sv, dead before 4a)
  //   [4608,9216)   sBtp s0..s3 (ph2 wr, ph3 rd; aliases sv)
  //   [9920,14528)  sE s0..s3: f16[32][72] (ph3 wr, 4a rd)
  //   [9920,9984)   swpart [64] (init wr, combine rd pre-ph2; sE later)
  //   [14528,15040) wB [16][32] uint I2W B-frags
  //   [15040,15048) sW [8]
  //   [15048,15544) ptab32 [496] u32: (i*36)<<16 | (j*36)
  __shared__ __align__(16) float smem[15544];
  unsigned*       sEd0 = (unsigned*)(smem + 9920);   // dword view of f16 E
  unsigned*       wB   = (unsigned*)(smem + 14528);  // [16][32]
  float*          sW   = smem + 15040;               // [8]
  unsigned*       ptab32 = (unsigned*)(smem + 15048); // [496]
  float*          swpart = smem + 9920;              // [64] (aliases sE s0)

  const int t  = threadIdx.x;
  const int s0 = blockIdx.x * 4;

  // ---- init (no barrier after; consumers are beyond later barriers) ----
  if (t < 64) {                                // sW partials (distributed)
    const int f = t >> 3, seg = t & 7;
    const float4 a = *(const float4*)(I2W + f * HID + seg * 8);
    const float4 b = *(const float4*)(I2W + f * HID + seg * 8 + 4);
    swpart[t] = ((a.x + a.y) + (a.z + a.w)) + ((b.x + b.y) + (b.z + b.w));
  }
  #pragma unroll
  for (int idx = t; idx < 512; idx += 256) {   // wB[n][k2]; rows 8-15 zero
    const int n = idx >> 5, k2 = idx & 31;
    wB[idx] = (n < IFEAT)
      ? pbits(pack2(I2W[n * HID + 2 * k2], I2W[n * HID + 2 * k2 + 1])) : 0u;
  }
  #pragma unroll
  for (int q = t; q < NPAIR_HALF; q += 256) {  // 4a table: premult row offsets
    int i, j; pair_decode(q, i, j);
    ptab32[q] = ((unsigned)(i * 36) << 16) | (unsigned)(j * 36);
  }

  // ---- phase 1: h1 = relu(x @ L1W^T + L1b) for 4 seq; x from global (L2);
  // weights shared across ss. pack f16 -> sAtp(ss)[n][k2] ----
  {
    const int n = t & 31, gI = t >> 5, kb = gI * 8;
    float4 xv[4];
    #pragma unroll
    for (int ss = 0; ss < 4; ++ss)
      xv[ss] = *(const float4*)(x + (s0 + ss) * 128 + n * 4);
    float a[4][8];
    #pragma unroll
    for (int r = 0; r < 8; ++r) {
      const int k = kb + r;
      const float4 w = *(const float4*)(L1W + k * 4);   // shared across ss
      const float bias = L1b[k];
      #pragma unroll
      for (int ss = 0; ss < 4; ++ss) {
        float v = bias;
        v = fmaf(xv[ss].x, w.x, v); v = fmaf(xv[ss].y, w.y, v);
        v = fmaf(xv[ss].z, w.z, v); v = fmaf(xv[ss].w, w.w, v);
        a[ss][r] = fmaxf(v, 0.0f);
      }
    }
    #pragma unroll
    for (int ss = 0; ss < 4; ++ss) {
      unsigned* sAtp = (unsigned*)(smem + ss * 1152);
      int4 pk;
      pk.x = (int)pbits(pack2(a[ss][0], a[ss][1]));
      pk.y = (int)pbits(pack2(a[ss][2], a[ss][3]));
      pk.z = (int)pbits(pack2(a[ss][4], a[ss][5]));
      pk.w = (int)pbits(pack2(a[ss][6], a[ss][7]));
      *(int4*)(sAtp + n * 36 + gI * 4) = pk;
    }
  }
  __syncthreads();

  if (t < IFEAT) {                             // combine sW partials
    float a = 0.0f;
    #pragma unroll
    for (int c = 0; c < 8; ++c) a += swpart[t * 8 + c];
    sW[t] = a;                                 // read in 4a (barriers cover)
  }

  const int lane = t & 63;
  const int wv   = t >> 6;        // wave id
  const int qd   = lane >> 4;     // quad 0..3
  const int ln   = lane & 15;

  // ---- phase 2: h2 = relu(h1 @ L2W^T + L2b) via MFMA; A-frags shared over
  // 4 ss; write sBtp directly (separate region -> no mid-barrier) ----
  {
    const int m = 16 * wv + ln;
    const float* wr = L2W + m * HID;
    const f16x8 A0 = pack8(*(const float4*)(wr + 8 * qd),
                           *(const float4*)(wr + 8 * qd + 4));
    const f16x8 A1 = pack8(*(const float4*)(wr + 32 + 8 * qd),
                           *(const float4*)(wr + 32 + 8 * qd + 4));
    const float4 bias = *(const float4*)(L2b + 16 * wv + 4 * qd);
    #pragma unroll
    for (int ss = 0; ss < 4; ++ss) {
      const unsigned* sAtp = (const unsigned*)(smem + ss * 1152);
      unsigned* sBtp = (unsigned*)(smem + 4608 + ss * 1152);
      #pragma unroll
      for (int nt = 0; nt < 2; ++nt) {
        const int n = nt * 16 + ln;
        const f16x8 B0 = __builtin_bit_cast(f16x8, *(const int4*)(sAtp + n * 36 + 4 * qd));
        const f16x8 B1 = __builtin_bit_cast(f16x8, *(const int4*)(sAtp + n * 36 + 16 + 4 * qd));
        f32x4 c; c[0] = bias.x; c[1] = bias.y; c[2] = bias.z; c[3] = bias.w;
        c = __builtin_amdgcn_mfma_f32_16x16x32_f16(A0, B0, c, 0, 0, 0);
        c = __builtin_amdgcn_mfma_f32_16x16x32_f16(A1, B1, c, 0, 0, 0);
        sBtp[n * 36 + 8 * wv + 2 * qd]     = pbits(pack2(fmaxf(c[0], 0.f), fmaxf(c[1], 0.f)));
        sBtp[n * 36 + 8 * wv + 2 * qd + 1] = pbits(pack2(fmaxf(c[2], 0.f), fmaxf(c[3], 0.f)));
      }
    }
  }
  __syncthreads();

  // ---- phase 3: g' = h2 @ (I1W*2log2e)^T via MFMA (scale folded into A);
  // A-frags shared over 4 ss; store E = exp2(g') as f16 pairs ----
  {
    const int m = 16 * wv + ln;
    const float* wr = I1W + m * HID;
    float4 w0 = *(const float4*)(wr + 8 * qd);
    float4 w1 = *(const float4*)(wr + 8 * qd + 4);
    float4 w2 = *(const float4*)(wr + 32 + 8 * qd);
    float4 w3 = *(const float4*)(wr + 32 + 8 * qd + 4);
    const float T = TWO_LOG2E;
    w0.x *= T; w0.y *= T; w0.z *= T; w0.w *= T;
    w1.x *= T; w1.y *= T; w1.z *= T; w1.w *= T;
    w2.x *= T; w2.y *= T; w2.z *= T; w2.w *= T;
    w3.x *= T; w3.y *= T; w3.z *= T; w3.w *= T;
    const f16x8 A0 = pack8(w0, w1);
    const f16x8 A1 = pack8(w2, w3);
    #pragma unroll
    for (int ss = 0; ss < 4; ++ss) {
      const unsigned* sBtp = (const unsigned*)(smem + 4608 + ss * 1152);
      unsigned* sEd = sEd0 + ss * 1152;
      #pragma unroll
      for (int nt = 0; nt < 2; ++nt) {
        const int n = nt * 16 + ln;
        const f16x8 B0 = __builtin_bit_cast(f16x8, *(const int4*)(sBtp + n * 36 + 4 * qd));
        const f16x8 B1 = __builtin_bit_cast(f16x8, *(const int4*)(sBtp + n * 36 + 16 + 4 * qd));
        f32x4 c; c[0] = 0.f; c[1] = 0.f; c[2] = 0.f; c[3] = 0.f;
        c = __builtin_amdgcn_mfma_f32_16x16x32_f16(A0, B0, c, 0, 0, 0);
        c = __builtin_amdgcn_mfma_f32_16x16x32_f16(A1, B1, c, 0, 0, 0);
        float e[4];
        #pragma unroll
        for (int r = 0; r < 4; ++r) {
          float gp = fminf(fmaxf(c[r], -GP_CLAMP), GP_CLAMP);   // c is g'
          e[r] = EXP2F(gp);
        }
        // mo = 16wv+4qd+r; f16 idx n*72+mo -> dword n*36 + 8wv + 2qd + {0,1}
        sEd[n * 36 + 8 * wv + 2 * qd]     = pbits(pack2(e[0], e[1]));
        sEd[n * 36 + 8 * wv + 2 * qd + 1] = pbits(pack2(e[2], e[3]));
      }
    }
  }
  __syncthreads();   // sBtp reads done + sE settled before 4a overwrites sv

  // ---- phase 4a: pair dots via MFMA; 4 ss per tile (2 ss-pairs), B-frags
  // and Wf amortized over 4 ss. A = fj * rcp8nr(ei + fj). tanh merged
  // across each ss-pair via DPP row_ror:8 (lanes 8-15 take the odd ss). ----
  {
    const f16x8 B0 = __builtin_bit_cast(f16x8, *(const int4*)(wB + ln * 32 + 4 * qd));
    const f16x8 B1 = __builtin_bit_cast(f16x8, *(const int4*)(wB + ln * 32 + 16 + 4 * qd));
    const float WfT = sW[ln & 7] * TWO_LOG2E;
    const float n2T = -2.0f * TWO_LOG2E;
    const bool lo = (ln < IFEAT);
    const int col = ln & 7;

    for (int tile = wv; tile < NTILE; tile += 4) {
      const unsigned pij = ptab32[tile * 16 + ln];   // (i*36)<<16 | (j*36)
      const int io = (int)(pij >> 16), jo = (int)(pij & 0xffffu);
      #pragma unroll
      for (int sp = 0; sp < 2; ++sp) {               // ss-pair: (2sp, 2sp+1)
        f32x4 c0, c1;
        #pragma unroll
        for (int half = 0; half < 2; ++half) {
          const unsigned* sEd = sEd0 + (2 * sp + half) * 1152;
          const f16x8 ei0 = __builtin_bit_cast(f16x8, *(const int4*)(sEd + io + 4 * qd));
          const f16x8 ei1 = __builtin_bit_cast(f16x8, *(const int4*)(sEd + io + 16 + 4 * qd));
          const f16x8 fj0 = __builtin_bit_cast(f16x8, *(const int4*)(sEd + jo + 4 * qd));
          const f16x8 fj1 = __builtin_bit_cast(f16x8, *(const int4*)(sEd + jo + 16 + 4 * qd));
          const f16x8 su0 = ei0 + fj0;               // v_pk_add_f16
          const f16x8 su1 = ei1 + fj1;
          const f16x8 A0 = fj0 * rcp8nr(su0);        // all full-rate pk ops
          const f16x8 A1 = fj1 * rcp8nr(su1);
          f32x4 c; c[0] = 0.f; c[1] = 0.f; c[2] = 0.f; c[3] = 0.f;
          c = __builtin_amdgcn_mfma_f32_16x16x32_f16(A0, B0, c, 0, 0, 0);
          c = __builtin_amdgcn_mfma_f32_16x16x32_f16(A1, B1, c, 0, 0, 0);
          if (half == 0) c0 = c; else c1 = c;
        }
        _Float16* svb = lo ? ((_Float16*)smem + (2 * sp) * 4960)
                           : ((_Float16*)smem + (2 * sp + 1) * 4960);
        #pragma unroll
        for (int r = 0; r < 4; ++r) {
          const float c1s = xor8_f32(c1[r]);        // odd-ss cols0-7 -> lanes 8-15
          const float m = lo ? c0[r] : c1s;
          // tanh(Wf - 2c) = 1 - 2/(exp2((Wf-2c)*T)+1), T-scale pre-folded
          const float arg = fmaf(n2T, m, WfT);
          const float e = EXP2F(arg);
          const float rr = __builtin_amdgcn_rcpf(e + 1.0f);
          const float v = fmaf(-2.0f, rr, 1.0f);
          svb[(tile * 16 + 4 * qd + r) * 10 + col] = (_Float16)v;
        }
      }
    }
  }
  __syncthreads();   // sv complete

  // ---- phase 4b (fused final): thread = (ss, i, d); full 31-m gather with
  // INLINE index calc; add self term; store directly (no part[], no extra
  // barrier). sv stride 10 f16 -> banks (5q+2d)%32, q-uniform. ----
  {
    const int ss = t >> 6, i = (t >> 1) & 31, d = t & 1;
    const _Float16* sv = (const _Float16*)smem + ss * 4960;
    const int Ci = pair_cum(i);
    float sum = 0.0f;
    #pragma unroll
    for (int m = 0; m < 31; ++m) {
      const bool up = (m >= i);                    // j = m+1 > i
      const int q = up ? (Ci + m - i) : (pair_cum(m) + i - m - 1);
      const h2* vp = (const h2*)(sv + q * 10 + d * 4);
      const h2 va = vp[0], vb = vp[1];
      const float4 cf = *(const float4*)(I3 + (i * 31 + m) * 8 + d * 4);
      const h2 ca = pack2(cf.x, cf.y);
      const h2 cb = pack2(cf.z, cf.w);
      float dot = dot2h(va, ca, 0.0f);
      dot = dot2h(vb, cb, dot);
      const float sgn = up ? 1.0f : -1.0f;
      sum = fmaf(sgn, dot, sum);
    }

    float res = S2b[i * 2 + d] + sum;
    const float4 xv = *(const float4*)(x + (s0 + ss) * 128 + i * 4);
    #pragma unroll
    for (int k = 0; k < 2; ++k) {
      const int f = d * 2 + k;
      float hs = S1b[f];
      hs = fmaf(xv.x, S1W[f * 4 + 0], hs);
      hs = fmaf(xv.y, S1W[f * 4 + 1], hs);
      hs = fmaf(xv.z, S1W[f * 4 + 2], hs);
      hs = fmaf(xv.w, S1W[f * 4 + 3], hs);
      hs = fmaxf(hs, 0.0f);
      res = fmaf(hs, S2W[i * 4 + d * 2 + k], res);
    }
    out[(s0 + ss) * (NOBJ * 2) + i * 2 + d] = res;
  }
}

extern "C" void kernel_launch(void* const* d_in, const int* in_sizes, int n_in,
                              void* d_out, int out_size, void* d_ws, size_t ws_size,
                              hipStream_t stream) {
  const float* x   = (const float*)d_in[0];
  const float* L1W = (const float*)d_in[1];
  const float* L1b = (const float*)d_in[2];
  const float* L2W = (const float*)d_in[3];
  const float* L2b = (const float*)d_in[4];
  const float* I1W = (const float*)d_in[5];
  const float* I2W = (const float*)d_in[6];
  const float* I3  = (const float*)d_in[7];
  const float* S1W = (const float*)d_in[8];
  const float* S1b = (const float*)d_in[9];
  const float* S2W = (const float*)d_in[10];
  const float* S2b = (const float*)d_in[11];
  float* outp = (float*)d_out;

  magnet_fused<<<SEQ / 4, 256, 0, stream>>>(x, L1W, L1b, L2W, L2b, I1W, I2W, I3,
                                            S1W, S1b, S2W, S2b, outp);
}